// Round 13
// baseline (217.252 us; speedup 1.0000x reference)
//
#include <hip/hip_runtime.h>
#include <hip/hip_bf16.h>
#include <math.h>

#define B_ 2
#define S_ 2048
#define D_ 1024
#define H_ 16
#define RANK_ 128
#define NC_ 16
#define DH_ 64
#define T_ (B_*S_)
#define NZ_ 2176          // Ct rows: 2048 Ct | 64 routers+pad | 64 unused
#define ZW_ 2048          // z row stride (score cols removed)

typedef __attribute__((ext_vector_type(8))) __bf16 bf16x8;
typedef __attribute__((ext_vector_type(8))) unsigned short u16x8;
typedef __attribute__((ext_vector_type(4))) unsigned short u16x4;
typedef __attribute__((ext_vector_type(4))) float f32x4;
typedef __attribute__((ext_vector_type(16))) float f32x16;

#if __has_builtin(__builtin_amdgcn_exp2f)
#define EXP2F(x) __builtin_amdgcn_exp2f(x)
#else
#define EXP2F(x) exp2f(x)
#endif

__device__ __forceinline__ unsigned short f2bu(float f) {
    __hip_bfloat16 h = __float2bfloat16(f);
    unsigned short u; __builtin_memcpy(&u, &h, 2); return u;
}
__device__ __forceinline__ float bu2f(unsigned short u) {
    __hip_bfloat16 h; __builtin_memcpy(&h, &u, 2); return __bfloat162float(h);
}

// async global->LDS 16B/lane; LDS dst = wave-uniform base (+ lane*16 implied)
__device__ __forceinline__ void gl_lds16(const unsigned short* g, unsigned short* l) {
    __builtin_amdgcn_global_load_lds(
        (const __attribute__((address_space(1))) void*)g,
        (__attribute__((address_space(3))) void*)l, 16, 0, 0);
}

// pack two f32 -> one u32 of 2x bf16 (lo -> [15:0])
__device__ __forceinline__ unsigned cvtpk_bf16(float lo, float hi) {
    unsigned r;
    asm("v_cvt_pk_bf16_f32 %0, %1, %2" : "=v"(r) : "v"(lo), "v"(hi));
    return r;
}
// swap hi 32 lanes of a with lo 32 lanes of b (both updated in place)
__device__ __forceinline__ void plswap(unsigned &a, unsigned &b) {
    asm("v_permlane32_swap_b32 %0, %1" : "+v"(a), "+v"(b));
}

__device__ __forceinline__ bool sniff_f32(const unsigned* __restrict__ p) {
    int votes = 0;
    #pragma unroll
    for (int i = 0; i < 64; i++) {
        unsigned e = (p[i] >> 23) & 0xFFu;
        votes += (e >= 0x60u && e <= 0x8Fu) ? 1 : 0;
    }
    return votes >= 32;
}

// ---------------------------------------------------------------------------
// merged input stage: blocks 0..511 = convert+transpose C; rest = flat converts
// (flat converts vectorized x4)
// ---------------------------------------------------------------------------
struct Cvt { const void* src[9]; unsigned short* dst[9]; const void* C; unsigned short* Ct; };

__global__ __launch_bounds__(256) void k_inputs(Cvt cv,
    const unsigned* __restrict__ probe)
{
    bool f32 = sniff_f32(probe);
    if (blockIdx.x < 512) {
        int bid = blockIdx.x;
        int d0 = (bid & 15) * 64, r0 = ((bid >> 4) & 1) * 64, n = bid >> 5;
        __shared__ unsigned short tile[64][65];
        for (int idx = threadIdx.x; idx < 4096; idx += 256) {
            int row = idx >> 6, col = idx & 63;
            size_t si = ((size_t)n*D_ + d0 + row)*RANK_ + r0 + col;
            tile[row][col] = f32 ? f2bu(((const float*)cv.C)[si])
                                 : ((const unsigned short*)cv.C)[si];
        }
        __syncthreads();
        for (int idx = threadIdx.x; idx < 4096; idx += 256) {
            int row = idx >> 6, col = idx & 63;
            cv.Ct[((size_t)(n*RANK_ + r0 + row))*D_ + d0 + col] = tile[col][row];
        }
        return;
    }
    const int offs[9] = {0, 4194304, 4210688, 4227072, 4243456,
                         4259840, 4390912, 4521984, 4653056};
    const int total4 = 5701632 / 4;
    int nconv = gridDim.x - 512;
    int stride = nconv * 256;
    for (int g = (blockIdx.x - 512) * 256 + threadIdx.x; g < total4; g += stride) {
        int i = g * 4;
        int seg = 0;
        #pragma unroll
        for (int s = 1; s < 9; s++) seg += (i >= offs[s]) ? 1 : 0;
        int local = i - offs[seg];
        const void* sp = cv.src[seg];
        u16x4 v = {0, 0, 0, 0};
        if (sp) {
            if (f32) {
                f32x4 x = *(const f32x4*)((const float*)sp + local);
                #pragma unroll
                for (int j = 0; j < 4; j++) v[j] = f2bu(x[j]);
            } else {
                v = *(const u16x4*)((const unsigned short*)sp + local);
            }
        }
        *(u16x4*)(cv.dst[seg] + local) = v;
    }
}

// ---------------------------------------------------------------------------
// MFMA NT GEMM, async-staged. Tile (MT*32)x128, BK=32.
// MODE: 0 = bf16 out; 2 = runtime-sniffed out dtype (fp32 vs bf16)
// ---------------------------------------------------------------------------
template<int MT, int MODE>
__global__ __launch_bounds__(256) void k_mfma_gemm(const unsigned short* __restrict__ A,
    const unsigned short* __restrict__ Bm, void* __restrict__ Cout,
    const unsigned* __restrict__ probe, int M, int N, int K)
{
    bool f32out = false;
    if (MODE == 2) f32out = sniff_f32(probe);
    __shared__ __align__(16) unsigned short As[MT*32*32];
    __shared__ __align__(16) unsigned short Bs[128*32];
    const int tid = threadIdx.x;
    const int wv = tid >> 6, lane = tid & 63;
    const int wm = (wv >> 1) * (MT*16), wn = (wv & 1) * 64;
    const int quad = lane >> 4, l16 = lane & 15;
    const int m0 = blockIdx.x * (MT*32), n0 = blockIdx.y * 128;

    const f32x4 z4 = {0.f, 0.f, 0.f, 0.f};
    f32x4 acc[MT][4];
    #pragma unroll
    for (int i = 0; i < MT; i++)
        #pragma unroll
        for (int j = 0; j < 4; j++) acc[i][j] = z4;

    for (int k0 = 0; k0 < K; k0 += 32) {
        __syncthreads();
        #pragma unroll
        for (int c = 0; c < MT/2; c++) {
            int idx = wv*64 + c*256 + lane;
            gl_lds16(A + (size_t)(m0 + (idx >> 2))*K + k0 + (idx & 3)*8,
                     &As[(wv*64 + c*256)*8]);
        }
        #pragma unroll
        for (int c = 0; c < 2; c++) {
            int idx = wv*64 + c*256 + lane;
            gl_lds16(Bm + (size_t)(n0 + (idx >> 2))*K + k0 + (idx & 3)*8,
                     &Bs[(wv*64 + c*256)*8]);
        }
        __syncthreads();
        bf16x8 af[MT], bfr[4];
        #pragma unroll
        for (int mt = 0; mt < MT; mt++) af[mt]  = *(const bf16x8*)&As[(wm + mt*16 + l16)*32 + quad*8];
        #pragma unroll
        for (int nt = 0; nt < 4; nt++) bfr[nt] = *(const bf16x8*)&Bs[(wn + nt*16 + l16)*32 + quad*8];
        #pragma unroll
        for (int mt = 0; mt < MT; mt++)
            #pragma unroll
            for (int nt = 0; nt < 4; nt++)
                acc[mt][nt] = __builtin_amdgcn_mfma_f32_16x16x32_bf16(af[mt], bfr[nt], acc[mt][nt], 0, 0, 0);
    }
    #pragma unroll
    for (int mt = 0; mt < MT; mt++)
        #pragma unroll
        for (int nt = 0; nt < 4; nt++) {
            int col = n0 + wn + nt*16 + l16;
            #pragma unroll
            for (int r = 0; r < 4; r++) {
                int rowg = m0 + wm + mt*16 + quad*4 + r;
                float v = acc[mt][nt][r];
                if (MODE == 2 && f32out) ((float*)Cout)[(size_t)rowg*N + col] = v;
                else  ((unsigned short*)Cout)[(size_t)rowg*N + col] = f2bu(v);
            }
        }
}

// ---------------------------------------------------------------------------
// MERGED z-GEMM + router-score GEMM, one 768-block launch.
//   blocks 0..511  : z = xc @ Ct^T   (128x128 tiles, MT=4; 2 blocks/CU)
//   blocks 512..767: spart[kc] = xc[:, kc*128..+128] @ Rt^T (1 block/CU)
// ---------------------------------------------------------------------------
__global__ __launch_bounds__(256) void k_zscore(const unsigned short* __restrict__ xc,
    const unsigned short* __restrict__ Ct, unsigned short* __restrict__ z,
    const unsigned short* __restrict__ Rt, float* __restrict__ spart)
{
    __shared__ __align__(16) unsigned short As[128*32];
    __shared__ __align__(16) unsigned short Bs[128*32];
    const int tid = threadIdx.x;
    const int wv = tid >> 6, lane = tid & 63;
    const int quad = lane >> 4, l16 = lane & 15;
    const f32x4 z4 = {0.f, 0.f, 0.f, 0.f};

    if (blockIdx.x < 512) {
        // ---- z-GEMM path (MT=4) ----
        const int wm = (wv >> 1) * 64, wn = (wv & 1) * 64;
        const int m0 = (blockIdx.x & 31) * 128, n0 = (blockIdx.x >> 5) * 128;
        f32x4 acc[4][4];
        #pragma unroll
        for (int i = 0; i < 4; i++)
            #pragma unroll
            for (int j = 0; j < 4; j++) acc[i][j] = z4;

        for (int k0 = 0; k0 < D_; k0 += 32) {
            __syncthreads();
            #pragma unroll
            for (int c = 0; c < 2; c++) {
                int idx = wv*64 + c*256 + lane;
                gl_lds16(xc + (size_t)(m0 + (idx >> 2))*D_ + k0 + (idx & 3)*8,
                         &As[(wv*64 + c*256)*8]);
                gl_lds16(Ct + (size_t)(n0 + (idx >> 2))*D_ + k0 + (idx & 3)*8,
                         &Bs[(wv*64 + c*256)*8]);
            }
            __syncthreads();
            bf16x8 af[4], bfr[4];
            #pragma unroll
            for (int mt = 0; mt < 4; mt++) af[mt]  = *(const bf16x8*)&As[(wm + mt*16 + l16)*32 + quad*8];
            #pragma unroll
            for (int nt = 0; nt < 4; nt++) bfr[nt] = *(const bf16x8*)&Bs[(wn + nt*16 + l16)*32 + quad*8];
            #pragma unroll
            for (int mt = 0; mt < 4; mt++)
                #pragma unroll
                for (int nt = 0; nt < 4; nt++)
                    acc[mt][nt] = __builtin_amdgcn_mfma_f32_16x16x32_bf16(af[mt], bfr[nt], acc[mt][nt], 0, 0, 0);
        }
        #pragma unroll
        for (int mt = 0; mt < 4; mt++)
            #pragma unroll
            for (int nt = 0; nt < 4; nt++) {
                int col = n0 + wn + nt*16 + l16;
                #pragma unroll
                for (int r = 0; r < 4; r++) {
                    int rowg = m0 + wm + mt*16 + quad*4 + r;
                    z[(size_t)rowg*ZW_ + col] = f2bu(acc[mt][nt][r]);
                }
            }
    } else {
        // ---- router-score path ----
        const int id = blockIdx.x - 512;
        const int m0 = (id & 31) * 128;
        const int kc = id >> 5;                // K-chunk 0..7 (128 wide)
        const int wm = wv * 32;                // wave's 32 token-rows
        f32x4 acc[2][4];
        #pragma unroll
        for (int i = 0; i < 2; i++)
            #pragma unroll
            for (int j = 0; j < 4; j++) acc[i][j] = z4;

        for (int k0 = kc*128; k0 < kc*128 + 128; k0 += 32) {
            __syncthreads();
            #pragma unroll
            for (int c = 0; c < 2; c++) {
                int idx = wv*64 + c*256 + lane;
                gl_lds16(xc + (size_t)(m0 + (idx >> 2))*D_ + k0 + (idx & 3)*8,
                         &As[(wv*64 + c*256)*8]);
            }
            {
                int idx = wv*64 + lane;
                gl_lds16(Rt + (size_t)(idx >> 2)*D_ + k0 + (idx & 3)*8,
                         &Bs[(wv*64)*8]);
            }
            __syncthreads();
            bf16x8 af[2], bfr[4];
            #pragma unroll
            for (int mt = 0; mt < 2; mt++) af[mt]  = *(const bf16x8*)&As[(wm + mt*16 + l16)*32 + quad*8];
            #pragma unroll
            for (int nt = 0; nt < 4; nt++) bfr[nt] = *(const bf16x8*)&Bs[(nt*16 + l16)*32 + quad*8];
            #pragma unroll
            for (int mt = 0; mt < 2; mt++)
                #pragma unroll
                for (int nt = 0; nt < 4; nt++)
                    acc[mt][nt] = __builtin_amdgcn_mfma_f32_16x16x32_bf16(af[mt], bfr[nt], acc[mt][nt], 0, 0, 0);
        }
        #pragma unroll
        for (int mt = 0; mt < 2; mt++)
            #pragma unroll
            for (int nt = 0; nt < 4; nt++) {
                int col = nt*16 + l16;
                #pragma unroll
                for (int r = 0; r < 4; r++) {
                    int rowg = m0 + wm + mt*16 + quad*4 + r;
                    spart[(size_t)kc*T_*64 + (size_t)rowg*64 + col] = acc[mt][nt][r];
                }
            }
    }
}

// ---------------------------------------------------------------------------
// hreduce + router softmax (scores = sum of 8 f32 K-chunk partials)
// ---------------------------------------------------------------------------
__global__ __launch_bounds__(256) void k_hreduce(const unsigned short* __restrict__ z,
    const float* __restrict__ spart, unsigned short* __restrict__ h)
{
    int t0 = blockIdx.x * 2;
    int tg = threadIdx.x >> 7, r = threadIdx.x & 127;
    int t = t0 + tg;
    __shared__ float sc[2][48];
    __shared__ float wl[2][3][16];
    if (threadIdx.x < 96) {
        int tk = threadIdx.x / 48, j = threadIdx.x % 48;
        float s = 0.f;
        #pragma unroll
        for (int p = 0; p < 8; p++)
            s += spart[(size_t)p*T_*64 + (size_t)(t0 + tk)*64 + j];
        sc[tk][j] = s;
    }
    __syncthreads();
    if (threadIdx.x < 6) {
        int tk = threadIdx.x / 3, w = threadIdx.x % 3;
        float m = -INFINITY;
        for (int n = 0; n < 16; n++) m = fmaxf(m, sc[tk][w*16 + n]);
        float s = 0.f, e[16];
        for (int n = 0; n < 16; n++) { e[n] = __expf(sc[tk][w*16 + n] - m); s += e[n]; }
        float inv = 1.f / s;
        for (int n = 0; n < 16; n++) wl[tk][w][n] = e[n] * inv;
    }
    __syncthreads();
    const unsigned short* zr = z + (size_t)t * ZW_;
    float acc[3] = {0.f, 0.f, 0.f};
    #pragma unroll
    for (int n = 0; n < NC_; n++) {
        float zv = bu2f(zr[n*RANK_ + r]);
        #pragma unroll
        for (int w = 0; w < 3; w++) acc[w] += wl[tg][w][n] * zv;
    }
    #pragma unroll
    for (int w = 0; w < 3; w++) h[((size_t)w*T_ + t)*RANK_ + r] = f2bu(acc[w]);
}

// ---------------------------------------------------------------------------
// merged Q|K + V^T GEMMs (K=128), one launch, 768 blocks.
// ---------------------------------------------------------------------------
__global__ __launch_bounds__(256) void k_qkv2(const unsigned short* __restrict__ h3,
    const unsigned short* __restrict__ wqkv, unsigned short* __restrict__ QKb,
    unsigned short* __restrict__ Vtg)
{
    __shared__ __align__(16) unsigned short As[128*32];
    __shared__ __align__(16) unsigned short Bs[128*32];
    const int tid = threadIdx.x;
    const int wv = tid >> 6, lane = tid & 63;
    const int wm = (wv >> 1) * 64, wn = (wv & 1) * 64;
    const int quad = lane >> 4, l16 = lane & 15;

    const bool vt = (blockIdx.x >= 512);
    int m0, n0;
    const unsigned short *A, *Bm;
    float scale = 1.f;
    if (!vt) {
        int id = blockIdx.x;
        m0 = (id & 31) * 128;                 // tokens
        n0 = (id >> 5) * 128;                 // Q|K cols (0..2047)
        int w = n0 >> 10;
        A  = h3 + (size_t)w * T_ * RANK_ + (size_t)m0 * RANK_;
        Bm = wqkv + (size_t)w * D_ * RANK_ + (size_t)(n0 & 1023) * RANK_;
        if (w == 0) scale = 0.125f * 1.44269504f;
    } else {
        int id = blockIdx.x - 512;
        m0 = (id & 7) * 128;                  // dv rows
        n0 = (id >> 3) * 128;                 // tokens
        A  = wqkv + (size_t)2 * D_ * RANK_ + (size_t)m0 * RANK_;
        Bm = h3 + (size_t)2 * T_ * RANK_ + (size_t)n0 * RANK_;
    }

    const f32x4 z4 = {0.f, 0.f, 0.f, 0.f};
    f32x4 acc[4][4];
    #pragma unroll
    for (int i = 0; i < 4; i++)
        #pragma unroll
        for (int j = 0; j < 4; j++) acc[i][j] = z4;

    for (int k0 = 0; k0 < RANK_; k0 += 32) {
        __syncthreads();
        #pragma unroll
        for (int c = 0; c < 2; c++) {
            int idx = wv*64 + c*256 + lane;
            gl_lds16(A  + (size_t)(idx >> 2)*RANK_ + k0 + (idx & 3)*8,
                     &As[(wv*64 + c*256)*8]);
            gl_lds16(Bm + (size_t)(idx >> 2)*RANK_ + k0 + (idx & 3)*8,
                     &Bs[(wv*64 + c*256)*8]);
        }
        __syncthreads();
        bf16x8 af[4], bfr[4];
        #pragma unroll
        for (int mt = 0; mt < 4; mt++) af[mt]  = *(const bf16x8*)&As[(wm + mt*16 + l16)*32 + quad*8];
        #pragma unroll
        for (int nt = 0; nt < 4; nt++) bfr[nt] = *(const bf16x8*)&Bs[(wn + nt*16 + l16)*32 + quad*8];
        #pragma unroll
        for (int mt = 0; mt < 4; mt++)
            #pragma unroll
            for (int nt = 0; nt < 4; nt++)
                acc[mt][nt] = __builtin_amdgcn_mfma_f32_16x16x32_bf16(af[mt], bfr[nt], acc[mt][nt], 0, 0, 0);
    }
    #pragma unroll
    for (int mt = 0; mt < 4; mt++)
        #pragma unroll
        for (int nt = 0; nt < 4; nt++) {
            #pragma unroll
            for (int r = 0; r < 4; r++) {
                int rowg = m0 + wm + mt*16 + quad*4 + r;
                int col  = n0 + wn + nt*16 + l16;
                float v = acc[mt][nt][r] * scale;
                if (!vt) {
                    QKb[(size_t)(col >> 10)*T_*D_ + (size_t)rowg*D_ + (col & 1023)]
                        = f2bu(v);
                } else {
                    size_t vrow = (size_t)((col >> 11)*H_ + (rowg >> 6))*64 + (rowg & 63);
                    Vtg[vrow*S_ + (col & 2047)] = f2bu(v);
                }
            }
        }
}

// ---------------------------------------------------------------------------
// MFMA causal flash attention — FOUR independent barrier groups per CU.
//   - 1024 blocks x 128 threads (2 waves), each owning a 64-token q-tile
//     with PRIVATE 2-ring K/V LDS (32 KiB) -> 4 blocks/CU = 128 KiB, 8
//     waves/CU in 4 independent barrier groups (R12 had 8 waves in 2 groups
//     that phase-lock -> near-zero pipe overlap, 2850 cyc/visit).
//   - Per-wave code identical to the proven R4/R12 inner loop: 32x32x16
//     swapped QK^T, lane-local exp2 softmax, in-register cvt_pk+permlane
//     pack, one barrier/iter with full-iteration DMA flight.
//   - Mapping x = slot*256 + ts*32 + gr: CU gets slots {31-ts, ts, 23-ts,
//     8+ts} -> 66 visits/CU CONSTANT (makespan-uniform); x%8==gr%8 keeps
//     XCD-clustered K/V.
// ---------------------------------------------------------------------------
__global__ __launch_bounds__(128) void k_flash_mfma(const unsigned short* __restrict__ Qm,
    const unsigned short* __restrict__ Km, const unsigned short* __restrict__ Vtg,
    unsigned short* __restrict__ Om)
{
    const int x = blockIdx.x;                  // 0..1023
    const int slot = x >> 8, rr = x & 255;
    const int ts = rr >> 5, gr = rr & 31;      // gr = (b,h) group; ts = 0..7
    int qt;                                    // 64-token q-tile, 0..31
    if      (slot == 0) qt = 31 - ts;
    else if (slot == 1) qt = ts;
    else if (slot == 2) qt = 23 - ts;
    else                qt = 8 + ts;
    const int hh = gr & 15, b = gr >> 4;

    __shared__ __align__(16) unsigned short Ks[2][64*64];  // [key][dh], xor-swz
    __shared__ __align__(16) unsigned short Vs[2][64*64];  // [dh][key], xor-swz
    const int tid = threadIdx.x;
    const int w = tid >> 6, lane = tid & 63;
    const int l32 = lane & 31, hi = lane >> 5;
    const size_t base  = ((size_t)b * S_) * D_ + (size_t)hh * DH_;
    const size_t vbase = (size_t)((b*H_ + hh) * 64) * S_;
    const int tokg = qt*64 + w*32 + l32;       // this lane's token (B-operand col)

    // Q fragments: B-operand, 4 dh-chunks of 16 (lane supplies k = hi*8..+8)
    bf16x8 aq[4];
    #pragma unroll
    for (int ks = 0; ks < 4; ks++)
        aq[ks] = *(const bf16x8*)(Qm + base + (size_t)tokg*D_ + ks*16 + hi*8);

    f32x16 oacc[2];
    #pragma unroll
    for (int db = 0; db < 2; db++)
        #pragma unroll
        for (int ii = 0; ii < 16; ii++) oacc[db][ii] = 0.f;
    float lsum = 0.f;

    const int nkt = qt + 1;                    // 64-key tiles up to the diagonal

    auto STAGE = [&](int kt_, int bf_) {
        #pragma unroll
        for (int c = 0; c < 4; c++) {          // K: 64 rows x 8 chunks
            int idx = c*128 + tid;
            int row = idx >> 3, j = (idx & 7) ^ (row & 7);
            gl_lds16(Km + base + (size_t)(kt_*64 + row)*D_ + j*8,
                     &Ks[bf_][(c*128 + (w<<6))*8]);
        }
        #pragma unroll
        for (int c = 0; c < 4; c++) {          // V^T: 64 dh rows x 8 chunks
            int idx = c*128 + tid;
            int row = idx >> 3, j = (idx & 7) ^ (row & 7);
            gl_lds16(Vtg + vbase + (size_t)row*S_ + kt_*64 + j*8,
                     &Vs[bf_][(c*128 + (w<<6))*8]);
        }
    };

    STAGE(0, 0);                               // prologue

    for (int kt = 0; kt < nkt; kt++) {
        const int cur = kt & 1;
        __syncthreads();                       // drains tile-kt DMA (full-iter flight)

        if (kt + 1 < nkt) STAGE(kt + 1, 1 - cur);

        // S^T = K Q^T (log2 domain): sacc[kb] = 32 keys x 32 toks, tok = lane col
        f32x16 sacc[2];
        #pragma unroll
        for (int kb = 0; kb < 2; kb++)
            #pragma unroll
            for (int ii = 0; ii < 16; ii++) sacc[kb][ii] = 0.f;
        #pragma unroll
        for (int ks = 0; ks < 4; ks++)
            #pragma unroll
            for (int kb = 0; kb < 2; kb++) {
                int row = kb*32 + l32;
                int c = (ks*2 + hi) ^ (row & 7);
                bf16x8 ak = *(const bf16x8*)&Ks[cur][row*64 + c*8];
                sacc[kb] = __builtin_amdgcn_mfma_f32_32x32x16_bf16(ak, aq[ks], sacc[kb], 0, 0, 0);
            }

        if (kt == qt) {                        // diagonal tile: causal mask
            #pragma unroll
            for (int kb = 0; kb < 2; kb++)
                #pragma unroll
                for (int r = 0; r < 16; r++) {
                    int keyg = kt*64 + kb*32 + (r&3) + 8*(r>>2) + 4*hi;
                    if (keyg > tokg) sacc[kb][r] = -INFINITY;
                }
        }

        // exp2 + in-register pack to PV A-fragments (cvt_pk + permlane32_swap)
        bf16x8 pa[4];
        #pragma unroll
        for (int kb = 0; kb < 2; kb++) {
            float pv[16];
            #pragma unroll
            for (int r = 0; r < 16; r++) {
                pv[r] = EXP2F(sacc[kb][r]);
                lsum += pv[r];
            }
            unsigned wd[8];
            #pragma unroll
            for (int j = 0; j < 8; j++) wd[j] = cvtpk_bf16(pv[2*j], pv[2*j+1]);
            plswap(wd[0], wd[2]); plswap(wd[1], wd[3]);
            plswap(wd[4], wd[6]); plswap(wd[5], wd[7]);
            union { unsigned u[4]; bf16x8 v; } u0, u1;
            u0.u[0]=wd[0]; u0.u[1]=wd[1]; u0.u[2]=wd[2]; u0.u[3]=wd[3];
            u1.u[0]=wd[4]; u1.u[1]=wd[5]; u1.u[2]=wd[6]; u1.u[3]=wd[7];
            pa[2*kb]   = u0.v;
            pa[2*kb+1] = u1.v;
        }

        // O += P V  (V^T staged as [dh][key]; B-operand rows = dh)
        #pragma unroll
        for (int ks = 0; ks < 4; ks++)
            #pragma unroll
            for (int db = 0; db < 2; db++) {
                int row = db*32 + l32;
                int c = (ks*2 + hi) ^ (row & 7);
                bf16x8 bv = *(const bf16x8*)&Vs[cur][row*64 + c*8];
                oacc[db] = __builtin_amdgcn_mfma_f32_32x32x16_bf16(pa[ks], bv, oacc[db], 0, 0, 0);
            }
    }

    // normalize + write: lane l<32 holds lsum for token l; O rows are reg-mapped
    float l = lsum + __shfl_xor(lsum, 32);
    float inv = 1.f / l;
    #pragma unroll
    for (int r = 0; r < 16; r++) {
        int crow = (r&3) + 8*(r>>2) + 4*hi;
        float invr = __shfl(inv, crow);
        size_t rowo = base + (size_t)(qt*64 + w*32 + crow)*D_;
        #pragma unroll
        for (int db = 0; db < 2; db++)
            Om[rowo + db*32 + l32] = f2bu(oacc[db][r] * invr);
    }
}

// ---------------------------------------------------------------------------
// launch
// ---------------------------------------------------------------------------
extern "C" void kernel_launch(void* const* d_in, const int* in_sizes, int n_in,
                              void* d_out, int out_size, void* d_ws, size_t ws_size,
                              hipStream_t stream)
{
    const unsigned* probe = (const unsigned*)d_in[0];

    unsigned short* u = (unsigned short*)d_ws;
    unsigned short* xc   = u;               size_t o = (size_t)T_*D_;
    unsigned short* wqkv = u + o;           o += (size_t)3*D_*RANK_;
    unsigned short* wOc  = u + o;           o += (size_t)D_*D_;
    unsigned short* Ct   = u + o;           o += (size_t)NZ_*D_;      // 2048 Ct | 64 routers | 64 unused
    unsigned short* h3   = u + o;           o += (size_t)3*T_*RANK_;
    unsigned short* QKb  = u + o;           o += (size_t)2*T_*D_;     // Q | K
    unsigned short* Vtg  = u + o;           o += (size_t)T_*D_;
    unsigned short* z    = u + o;           o += (size_t)T_*NZ_;      // stride ZW_=2048 used
    unsigned short* attnb= u + o;           o += (size_t)T_*D_;
    float* spart = (float*)(u + o);         o += (size_t)8*T_*64*2;   // 8 x T x 64 f32

    unsigned short* Rp = Ct + (size_t)2048*D_;
    unsigned short* Qb = QKb;
    unsigned short* Kb = QKb + (size_t)T_*D_;

    Cvt cv;
    cv.src[0] = d_in[0]; cv.dst[0] = xc;
    cv.src[1] = d_in[3]; cv.dst[1] = Rp;
    cv.src[2] = d_in[4]; cv.dst[2] = Rp + 16384;
    cv.src[3] = d_in[5]; cv.dst[3] = Rp + 32768;
    cv.src[4] = nullptr; cv.dst[4] = Rp + 49152;
    cv.src[5] = d_in[6]; cv.dst[5] = wqkv;
    cv.src[6] = d_in[7]; cv.dst[6] = wqkv + 131072;
    cv.src[7] = d_in[8]; cv.dst[7] = wqkv + 262144;
    cv.src[8] = d_in[9]; cv.dst[8] = wOc;
    cv.C = d_in[2]; cv.Ct = Ct;
    k_inputs<<<512 + 1024, 256, 0, stream>>>(cv, probe);

    k_zscore<<<768, 256, 0, stream>>>(xc, Ct, z, Rp, spart);

    k_hreduce<<<T_/2, 256, 0, stream>>>(z, spart, h3);

    k_qkv2<<<768, 256, 0, stream>>>(h3, wqkv, QKb, Vtg);

    k_flash_mfma<<<dim3(1024), 128, 0, stream>>>(Qb, Kb, Vtg, attnb);

    k_mfma_gemm<2,2><<<dim3(T_/64, D_/128), 256, 0, stream>>>(
        attnb, wOc, d_out, probe, T_, D_, D_);
}

// Round 14
// 208.239 us; speedup vs baseline: 1.0433x; 1.0433x over previous
//
#include <hip/hip_runtime.h>
#include <hip/hip_bf16.h>
#include <math.h>

#define B_ 2
#define S_ 2048
#define D_ 1024
#define H_ 16
#define RANK_ 128
#define NC_ 16
#define DH_ 64
#define T_ (B_*S_)
#define NZ_ 2176          // Ct rows: 2048 Ct | 64 routers+pad | 64 unused
#define ZW_ 2048          // z row stride (score cols removed)

typedef __attribute__((ext_vector_type(8))) __bf16 bf16x8;
typedef __attribute__((ext_vector_type(8))) unsigned short u16x8;
typedef __attribute__((ext_vector_type(4))) unsigned short u16x4;
typedef __attribute__((ext_vector_type(4))) float f32x4;
typedef __attribute__((ext_vector_type(16))) float f32x16;

#if __has_builtin(__builtin_amdgcn_exp2f)
#define EXP2F(x) __builtin_amdgcn_exp2f(x)
#else
#define EXP2F(x) exp2f(x)
#endif

__device__ __forceinline__ unsigned short f2bu(float f) {
    __hip_bfloat16 h = __float2bfloat16(f);
    unsigned short u; __builtin_memcpy(&u, &h, 2); return u;
}
__device__ __forceinline__ float bu2f(unsigned short u) {
    __hip_bfloat16 h; __builtin_memcpy(&h, &u, 2); return __bfloat162float(h);
}

// async global->LDS 16B/lane; LDS dst = wave-uniform base (+ lane*16 implied)
__device__ __forceinline__ void gl_lds16(const unsigned short* g, unsigned short* l) {
    __builtin_amdgcn_global_load_lds(
        (const __attribute__((address_space(1))) void*)g,
        (__attribute__((address_space(3))) void*)l, 16, 0, 0);
}

// pack two f32 -> one u32 of 2x bf16 (lo -> [15:0])
__device__ __forceinline__ unsigned cvtpk_bf16(float lo, float hi) {
    unsigned r;
    asm("v_cvt_pk_bf16_f32 %0, %1, %2" : "=v"(r) : "v"(lo), "v"(hi));
    return r;
}
// swap hi 32 lanes of a with lo 32 lanes of b (both updated in place)
__device__ __forceinline__ void plswap(unsigned &a, unsigned &b) {
    asm("v_permlane32_swap_b32 %0, %1" : "+v"(a), "+v"(b));
}

__device__ __forceinline__ bool sniff_f32(const unsigned* __restrict__ p) {
    int votes = 0;
    #pragma unroll
    for (int i = 0; i < 64; i++) {
        unsigned e = (p[i] >> 23) & 0xFFu;
        votes += (e >= 0x60u && e <= 0x8Fu) ? 1 : 0;
    }
    return votes >= 32;
}

// ---------------------------------------------------------------------------
// merged input stage: blocks 0..511 = convert+transpose C; rest = flat converts
// (flat converts vectorized x4)
// ---------------------------------------------------------------------------
struct Cvt { const void* src[9]; unsigned short* dst[9]; const void* C; unsigned short* Ct; };

__global__ __launch_bounds__(256) void k_inputs(Cvt cv,
    const unsigned* __restrict__ probe)
{
    bool f32 = sniff_f32(probe);
    if (blockIdx.x < 512) {
        int bid = blockIdx.x;
        int d0 = (bid & 15) * 64, r0 = ((bid >> 4) & 1) * 64, n = bid >> 5;
        __shared__ unsigned short tile[64][65];
        for (int idx = threadIdx.x; idx < 4096; idx += 256) {
            int row = idx >> 6, col = idx & 63;
            size_t si = ((size_t)n*D_ + d0 + row)*RANK_ + r0 + col;
            tile[row][col] = f32 ? f2bu(((const float*)cv.C)[si])
                                 : ((const unsigned short*)cv.C)[si];
        }
        __syncthreads();
        for (int idx = threadIdx.x; idx < 4096; idx += 256) {
            int row = idx >> 6, col = idx & 63;
            cv.Ct[((size_t)(n*RANK_ + r0 + row))*D_ + d0 + col] = tile[col][row];
        }
        return;
    }
    const int offs[9] = {0, 4194304, 4210688, 4227072, 4243456,
                         4259840, 4390912, 4521984, 4653056};
    const int total4 = 5701632 / 4;
    int nconv = gridDim.x - 512;
    int stride = nconv * 256;
    for (int g = (blockIdx.x - 512) * 256 + threadIdx.x; g < total4; g += stride) {
        int i = g * 4;
        int seg = 0;
        #pragma unroll
        for (int s = 1; s < 9; s++) seg += (i >= offs[s]) ? 1 : 0;
        int local = i - offs[seg];
        const void* sp = cv.src[seg];
        u16x4 v = {0, 0, 0, 0};
        if (sp) {
            if (f32) {
                f32x4 x = *(const f32x4*)((const float*)sp + local);
                #pragma unroll
                for (int j = 0; j < 4; j++) v[j] = f2bu(x[j]);
            } else {
                v = *(const u16x4*)((const unsigned short*)sp + local);
            }
        }
        *(u16x4*)(cv.dst[seg] + local) = v;
    }
}

// ---------------------------------------------------------------------------
// MFMA NT GEMM, async-staged. Tile (MT*32)x128, BK=32.
// MODE: 0 = bf16 out; 2 = runtime-sniffed out dtype (fp32 vs bf16)
// ---------------------------------------------------------------------------
template<int MT, int MODE>
__global__ __launch_bounds__(256) void k_mfma_gemm(const unsigned short* __restrict__ A,
    const unsigned short* __restrict__ Bm, void* __restrict__ Cout,
    const unsigned* __restrict__ probe, int M, int N, int K)
{
    bool f32out = false;
    if (MODE == 2) f32out = sniff_f32(probe);
    __shared__ __align__(16) unsigned short As[MT*32*32];
    __shared__ __align__(16) unsigned short Bs[128*32];
    const int tid = threadIdx.x;
    const int wv = tid >> 6, lane = tid & 63;
    const int wm = (wv >> 1) * (MT*16), wn = (wv & 1) * 64;
    const int quad = lane >> 4, l16 = lane & 15;
    const int m0 = blockIdx.x * (MT*32), n0 = blockIdx.y * 128;

    const f32x4 z4 = {0.f, 0.f, 0.f, 0.f};
    f32x4 acc[MT][4];
    #pragma unroll
    for (int i = 0; i < MT; i++)
        #pragma unroll
        for (int j = 0; j < 4; j++) acc[i][j] = z4;

    for (int k0 = 0; k0 < K; k0 += 32) {
        __syncthreads();
        #pragma unroll
        for (int c = 0; c < MT/2; c++) {
            int idx = wv*64 + c*256 + lane;
            gl_lds16(A + (size_t)(m0 + (idx >> 2))*K + k0 + (idx & 3)*8,
                     &As[(wv*64 + c*256)*8]);
        }
        #pragma unroll
        for (int c = 0; c < 2; c++) {
            int idx = wv*64 + c*256 + lane;
            gl_lds16(Bm + (size_t)(n0 + (idx >> 2))*K + k0 + (idx & 3)*8,
                     &Bs[(wv*64 + c*256)*8]);
        }
        __syncthreads();
        bf16x8 af[MT], bfr[4];
        #pragma unroll
        for (int mt = 0; mt < MT; mt++) af[mt]  = *(const bf16x8*)&As[(wm + mt*16 + l16)*32 + quad*8];
        #pragma unroll
        for (int nt = 0; nt < 4; nt++) bfr[nt] = *(const bf16x8*)&Bs[(wn + nt*16 + l16)*32 + quad*8];
        #pragma unroll
        for (int mt = 0; mt < MT; mt++)
            #pragma unroll
            for (int nt = 0; nt < 4; nt++)
                acc[mt][nt] = __builtin_amdgcn_mfma_f32_16x16x32_bf16(af[mt], bfr[nt], acc[mt][nt], 0, 0, 0);
    }
    #pragma unroll
    for (int mt = 0; mt < MT; mt++)
        #pragma unroll
        for (int nt = 0; nt < 4; nt++) {
            int col = n0 + wn + nt*16 + l16;
            #pragma unroll
            for (int r = 0; r < 4; r++) {
                int rowg = m0 + wm + mt*16 + quad*4 + r;
                float v = acc[mt][nt][r];
                if (MODE == 2 && f32out) ((float*)Cout)[(size_t)rowg*N + col] = v;
                else  ((unsigned short*)Cout)[(size_t)rowg*N + col] = f2bu(v);
            }
        }
}

// ---------------------------------------------------------------------------
// MERGED z-GEMM + router-score GEMM, one 768-block launch.
//   blocks 0..511  : z = xc @ Ct^T   (128x128 tiles, MT=4; 2 blocks/CU)
//   blocks 512..767: spart[kc] = xc[:, kc*128..+128] @ Rt^T (1 block/CU)
// ---------------------------------------------------------------------------
__global__ __launch_bounds__(256) void k_zscore(const unsigned short* __restrict__ xc,
    const unsigned short* __restrict__ Ct, unsigned short* __restrict__ z,
    const unsigned short* __restrict__ Rt, float* __restrict__ spart)
{
    __shared__ __align__(16) unsigned short As[128*32];
    __shared__ __align__(16) unsigned short Bs[128*32];
    const int tid = threadIdx.x;
    const int wv = tid >> 6, lane = tid & 63;
    const int quad = lane >> 4, l16 = lane & 15;
    const f32x4 z4 = {0.f, 0.f, 0.f, 0.f};

    if (blockIdx.x < 512) {
        // ---- z-GEMM path (MT=4) ----
        const int wm = (wv >> 1) * 64, wn = (wv & 1) * 64;
        const int m0 = (blockIdx.x & 31) * 128, n0 = (blockIdx.x >> 5) * 128;
        f32x4 acc[4][4];
        #pragma unroll
        for (int i = 0; i < 4; i++)
            #pragma unroll
            for (int j = 0; j < 4; j++) acc[i][j] = z4;

        for (int k0 = 0; k0 < D_; k0 += 32) {
            __syncthreads();
            #pragma unroll
            for (int c = 0; c < 2; c++) {
                int idx = wv*64 + c*256 + lane;
                gl_lds16(xc + (size_t)(m0 + (idx >> 2))*D_ + k0 + (idx & 3)*8,
                         &As[(wv*64 + c*256)*8]);
                gl_lds16(Ct + (size_t)(n0 + (idx >> 2))*D_ + k0 + (idx & 3)*8,
                         &Bs[(wv*64 + c*256)*8]);
            }
            __syncthreads();
            bf16x8 af[4], bfr[4];
            #pragma unroll
            for (int mt = 0; mt < 4; mt++) af[mt]  = *(const bf16x8*)&As[(wm + mt*16 + l16)*32 + quad*8];
            #pragma unroll
            for (int nt = 0; nt < 4; nt++) bfr[nt] = *(const bf16x8*)&Bs[(wn + nt*16 + l16)*32 + quad*8];
            #pragma unroll
            for (int mt = 0; mt < 4; mt++)
                #pragma unroll
                for (int nt = 0; nt < 4; nt++)
                    acc[mt][nt] = __builtin_amdgcn_mfma_f32_16x16x32_bf16(af[mt], bfr[nt], acc[mt][nt], 0, 0, 0);
        }
        #pragma unroll
        for (int mt = 0; mt < 4; mt++)
            #pragma unroll
            for (int nt = 0; nt < 4; nt++) {
                int col = n0 + wn + nt*16 + l16;
                #pragma unroll
                for (int r = 0; r < 4; r++) {
                    int rowg = m0 + wm + mt*16 + quad*4 + r;
                    z[(size_t)rowg*ZW_ + col] = f2bu(acc[mt][nt][r]);
                }
            }
    } else {
        // ---- router-score path ----
        const int id = blockIdx.x - 512;
        const int m0 = (id & 31) * 128;
        const int kc = id >> 5;                // K-chunk 0..7 (128 wide)
        const int wm = wv * 32;                // wave's 32 token-rows
        f32x4 acc[2][4];
        #pragma unroll
        for (int i = 0; i < 2; i++)
            #pragma unroll
            for (int j = 0; j < 4; j++) acc[i][j] = z4;

        for (int k0 = kc*128; k0 < kc*128 + 128; k0 += 32) {
            __syncthreads();
            #pragma unroll
            for (int c = 0; c < 2; c++) {
                int idx = wv*64 + c*256 + lane;
                gl_lds16(xc + (size_t)(m0 + (idx >> 2))*D_ + k0 + (idx & 3)*8,
                         &As[(wv*64 + c*256)*8]);
            }
            {
                int idx = wv*64 + lane;
                gl_lds16(Rt + (size_t)(idx >> 2)*D_ + k0 + (idx & 3)*8,
                         &Bs[(wv*64)*8]);
            }
            __syncthreads();
            bf16x8 af[2], bfr[4];
            #pragma unroll
            for (int mt = 0; mt < 2; mt++) af[mt]  = *(const bf16x8*)&As[(wm + mt*16 + l16)*32 + quad*8];
            #pragma unroll
            for (int nt = 0; nt < 4; nt++) bfr[nt] = *(const bf16x8*)&Bs[(nt*16 + l16)*32 + quad*8];
            #pragma unroll
            for (int mt = 0; mt < 2; mt++)
                #pragma unroll
                for (int nt = 0; nt < 4; nt++)
                    acc[mt][nt] = __builtin_amdgcn_mfma_f32_16x16x32_bf16(af[mt], bfr[nt], acc[mt][nt], 0, 0, 0);
        }
        #pragma unroll
        for (int mt = 0; mt < 2; mt++)
            #pragma unroll
            for (int nt = 0; nt < 4; nt++) {
                int col = nt*16 + l16;
                #pragma unroll
                for (int r = 0; r < 4; r++) {
                    int rowg = m0 + wm + mt*16 + quad*4 + r;
                    spart[(size_t)kc*T_*64 + (size_t)rowg*64 + col] = acc[mt][nt][r];
                }
            }
    }
}

// ---------------------------------------------------------------------------
// hreduce + router softmax (scores = sum of 8 f32 K-chunk partials)
// ---------------------------------------------------------------------------
__global__ __launch_bounds__(256) void k_hreduce(const unsigned short* __restrict__ z,
    const float* __restrict__ spart, unsigned short* __restrict__ h)
{
    int t0 = blockIdx.x * 2;
    int tg = threadIdx.x >> 7, r = threadIdx.x & 127;
    int t = t0 + tg;
    __shared__ float sc[2][48];
    __shared__ float wl[2][3][16];
    if (threadIdx.x < 96) {
        int tk = threadIdx.x / 48, j = threadIdx.x % 48;
        float s = 0.f;
        #pragma unroll
        for (int p = 0; p < 8; p++)
            s += spart[(size_t)p*T_*64 + (size_t)(t0 + tk)*64 + j];
        sc[tk][j] = s;
    }
    __syncthreads();
    if (threadIdx.x < 6) {
        int tk = threadIdx.x / 3, w = threadIdx.x % 3;
        float m = -INFINITY;
        for (int n = 0; n < 16; n++) m = fmaxf(m, sc[tk][w*16 + n]);
        float s = 0.f, e[16];
        for (int n = 0; n < 16; n++) { e[n] = __expf(sc[tk][w*16 + n] - m); s += e[n]; }
        float inv = 1.f / s;
        for (int n = 0; n < 16; n++) wl[tk][w][n] = e[n] * inv;
    }
    __syncthreads();
    const unsigned short* zr = z + (size_t)t * ZW_;
    float acc[3] = {0.f, 0.f, 0.f};
    #pragma unroll
    for (int n = 0; n < NC_; n++) {
        float zv = bu2f(zr[n*RANK_ + r]);
        #pragma unroll
        for (int w = 0; w < 3; w++) acc[w] += wl[tg][w][n] * zv;
    }
    #pragma unroll
    for (int w = 0; w < 3; w++) h[((size_t)w*T_ + t)*RANK_ + r] = f2bu(acc[w]);
}

// ---------------------------------------------------------------------------
// merged Q|K + V^T GEMMs (K=128), one launch, 768 blocks.
// ---------------------------------------------------------------------------
__global__ __launch_bounds__(256) void k_qkv2(const unsigned short* __restrict__ h3,
    const unsigned short* __restrict__ wqkv, unsigned short* __restrict__ QKb,
    unsigned short* __restrict__ Vtg)
{
    __shared__ __align__(16) unsigned short As[128*32];
    __shared__ __align__(16) unsigned short Bs[128*32];
    const int tid = threadIdx.x;
    const int wv = tid >> 6, lane = tid & 63;
    const int wm = (wv >> 1) * 64, wn = (wv & 1) * 64;
    const int quad = lane >> 4, l16 = lane & 15;

    const bool vt = (blockIdx.x >= 512);
    int m0, n0;
    const unsigned short *A, *Bm;
    float scale = 1.f;
    if (!vt) {
        int id = blockIdx.x;
        m0 = (id & 31) * 128;                 // tokens
        n0 = (id >> 5) * 128;                 // Q|K cols (0..2047)
        int w = n0 >> 10;
        A  = h3 + (size_t)w * T_ * RANK_ + (size_t)m0 * RANK_;
        Bm = wqkv + (size_t)w * D_ * RANK_ + (size_t)(n0 & 1023) * RANK_;
        if (w == 0) scale = 0.125f * 1.44269504f;
    } else {
        int id = blockIdx.x - 512;
        m0 = (id & 7) * 128;                  // dv rows
        n0 = (id >> 3) * 128;                 // tokens
        A  = wqkv + (size_t)2 * D_ * RANK_ + (size_t)m0 * RANK_;
        Bm = h3 + (size_t)2 * T_ * RANK_ + (size_t)n0 * RANK_;
    }

    const f32x4 z4 = {0.f, 0.f, 0.f, 0.f};
    f32x4 acc[4][4];
    #pragma unroll
    for (int i = 0; i < 4; i++)
        #pragma unroll
        for (int j = 0; j < 4; j++) acc[i][j] = z4;

    for (int k0 = 0; k0 < RANK_; k0 += 32) {
        __syncthreads();
        #pragma unroll
        for (int c = 0; c < 2; c++) {
            int idx = wv*64 + c*256 + lane;
            gl_lds16(A  + (size_t)(idx >> 2)*RANK_ + k0 + (idx & 3)*8,
                     &As[(wv*64 + c*256)*8]);
            gl_lds16(Bm + (size_t)(idx >> 2)*RANK_ + k0 + (idx & 3)*8,
                     &Bs[(wv*64 + c*256)*8]);
        }
        __syncthreads();
        bf16x8 af[4], bfr[4];
        #pragma unroll
        for (int mt = 0; mt < 4; mt++) af[mt]  = *(const bf16x8*)&As[(wm + mt*16 + l16)*32 + quad*8];
        #pragma unroll
        for (int nt = 0; nt < 4; nt++) bfr[nt] = *(const bf16x8*)&Bs[(wn + nt*16 + l16)*32 + quad*8];
        #pragma unroll
        for (int mt = 0; mt < 4; mt++)
            #pragma unroll
            for (int nt = 0; nt < 4; nt++)
                acc[mt][nt] = __builtin_amdgcn_mfma_f32_16x16x32_bf16(af[mt], bfr[nt], acc[mt][nt], 0, 0, 0);
    }
    #pragma unroll
    for (int mt = 0; mt < 4; mt++)
        #pragma unroll
        for (int nt = 0; nt < 4; nt++) {
            #pragma unroll
            for (int r = 0; r < 4; r++) {
                int rowg = m0 + wm + mt*16 + quad*4 + r;
                int col  = n0 + wn + nt*16 + l16;
                float v = acc[mt][nt][r] * scale;
                if (!vt) {
                    QKb[(size_t)(col >> 10)*T_*D_ + (size_t)rowg*D_ + (col & 1023)]
                        = f2bu(v);
                } else {
                    size_t vrow = (size_t)((col >> 11)*H_ + (rowg >> 6))*64 + (rowg & 63);
                    Vtg[vrow*S_ + (col & 2047)] = f2bu(v);
                }
            }
        }
}

// ---------------------------------------------------------------------------
// MFMA causal flash attention — R4 structure + T15 cross-iteration skew.
//   (R12 version — best measured; R13's 2-wave/4-group variant doubled
//   staging work and regressed, reverted)
// ---------------------------------------------------------------------------
__global__ __launch_bounds__(256, 2) void k_flash_mfma(const unsigned short* __restrict__ Qm,
    const unsigned short* __restrict__ Km, const unsigned short* __restrict__ Vtg,
    unsigned short* __restrict__ Om)
{
    const int i = blockIdx.x;                  // 0..511
    const int half = i >> 8, r_ = i & 255;
    const int gr = r_ & 31, ts = r_ >> 5;      // gr = (b,h) group; ts = 0..7
    const int qt = half ? ts : (15 - ts);      // complementary halves
    const int hh = gr & 15, b = gr >> 4;

    __shared__ __align__(16) unsigned short Ks[3][64*64];  // [key][dh], xor-swz
    __shared__ __align__(16) unsigned short Vs[3][64*64];  // [dh][key], xor-swz
    const int tid = threadIdx.x;
    const int w = tid >> 6, lane = tid & 63;
    const int l32 = lane & 31, hi = lane >> 5;
    const size_t base  = ((size_t)b * S_) * D_ + (size_t)hh * DH_;
    const size_t vbase = (size_t)((b*H_ + hh) * 64) * S_;
    const int tokg = qt*128 + w*32 + l32;      // this lane's token (B-operand col)

    // Q fragments: B-operand, 4 dh-chunks of 16 (lane supplies k = hi*8..+8)
    bf16x8 aq[4];
    #pragma unroll
    for (int ks = 0; ks < 4; ks++)
        aq[ks] = *(const bf16x8*)(Qm + base + (size_t)tokg*D_ + ks*16 + hi*8);

    f32x16 oacc[2];
    #pragma unroll
    for (int db = 0; db < 2; db++)
        #pragma unroll
        for (int ii = 0; ii < 16; ii++) oacc[db][ii] = 0.f;
    float lsum = 0.f;

    const int nkt = 2*(qt + 1);                // 64-key tiles up to the diagonal

    auto STAGE = [&](int kt_, int bf_) {
        #pragma unroll
        for (int c = 0; c < 2; c++) {
            int idx = c*256 + tid;
            int row = idx >> 3, j = (idx & 7) ^ (row & 7);
            gl_lds16(Km + base + (size_t)(kt_*64 + row)*D_ + j*8,
                     &Ks[bf_][(c*256 + (w<<6))*8]);
        }
        #pragma unroll
        for (int c = 0; c < 2; c++) {
            int idx = c*256 + tid;
            int row = idx >> 3, j = (idx & 7) ^ (row & 7);
            gl_lds16(Vtg + vbase + (size_t)row*S_ + kt_*64 + j*8,
                     &Vs[bf_][(c*256 + (w<<6))*8]);
        }
    };

    // S^T = K Q^T (log2 domain) for tile kt_ -> (s0,s1) = 2x (32 keys x 32 toks)
    auto QKT = [&](int bf_, f32x16& s0, f32x16& s1) {
        #pragma unroll
        for (int ii = 0; ii < 16; ii++) { s0[ii] = 0.f; s1[ii] = 0.f; }
        const unsigned short* Kp = Ks[bf_];
        #pragma unroll
        for (int ks = 0; ks < 4; ks++) {
            int c0 = (ks*2 + hi) ^ (l32 & 7);
            bf16x8 ak0 = *(const bf16x8*)&Kp[l32*64 + c0*8];
            s0 = __builtin_amdgcn_mfma_f32_32x32x16_bf16(ak0, aq[ks], s0, 0, 0, 0);
            int row1 = 32 + l32;
            int c1 = (ks*2 + hi) ^ (row1 & 7);
            bf16x8 ak1 = *(const bf16x8*)&Kp[row1*64 + c1*8];
            s1 = __builtin_amdgcn_mfma_f32_32x32x16_bf16(ak1, aq[ks], s1, 0, 0, 0);
        }
    };

    STAGE(0, 0);
    STAGE(1, 1);                               // nkt >= 2 always
    __syncthreads();                           // tiles 0 and 1 resident

    f32x16 sA0, sA1, sB0, sB1;
    QKT(0, sA0, sA1);

    for (int kt = 0; kt < nkt; kt++) {
        const int cur = kt % 3;
        if (kt + 2 < nkt) STAGE(kt + 2, (kt + 2) % 3);  // overwrites buf (kt-1)%3: readers done pre-barrier
        if (kt + 1 < nkt) QKT((kt + 1) % 3, sB0, sB1);  // tile kt+1 drained by last barrier

        if (kt >= 2*qt) {                      // diagonal tiles: causal mask (on sA)
            #pragma unroll
            for (int r = 0; r < 16; r++) {
                int crow = (r&3) + 8*(r>>2) + 4*hi;
                int keyg0 = kt*64 + crow;
                int keyg1 = kt*64 + 32 + crow;
                if (keyg0 > tokg) sA0[r] = -INFINITY;
                if (keyg1 > tokg) sA1[r] = -INFINITY;
            }
        }

        // exp2 + in-register pack to PV A-fragments (cvt_pk + permlane32_swap)
        bf16x8 pa[4];
        #pragma unroll
        for (int kb = 0; kb < 2; kb++) {
            float pv[16];
            #pragma unroll
            for (int r = 0; r < 16; r++) {
                pv[r] = EXP2F(kb ? sA1[r] : sA0[r]);
                lsum += pv[r];
            }
            unsigned wd[8];
            #pragma unroll
            for (int j = 0; j < 8; j++) wd[j] = cvtpk_bf16(pv[2*j], pv[2*j+1]);
            plswap(wd[0], wd[2]); plswap(wd[1], wd[3]);
            plswap(wd[4], wd[6]); plswap(wd[5], wd[7]);
            union { unsigned u[4]; bf16x8 v; } u0, u1;
            u0.u[0]=wd[0]; u0.u[1]=wd[1]; u0.u[2]=wd[2]; u0.u[3]=wd[3];
            u1.u[0]=wd[4]; u1.u[1]=wd[5]; u1.u[2]=wd[6]; u1.u[3]=wd[7];
            pa[2*kb]   = u0.v;
            pa[2*kb+1] = u1.v;
        }

        // O += P V  (V^T staged as [dh][key]; B-operand rows = dh)
        #pragma unroll
        for (int ks = 0; ks < 4; ks++)
            #pragma unroll
            for (int db = 0; db < 2; db++) {
                int row = db*32 + l32;
                int c = (ks*2 + hi) ^ (row & 7);
                bf16x8 bv = *(const bf16x8*)&Vs[cur][row*64 + c*8];
                oacc[db] = __builtin_amdgcn_mfma_f32_32x32x16_bf16(pa[ks], bv, oacc[db], 0, 0, 0);
            }

        if (kt + 1 < nkt) { sA0 = sB0; sA1 = sB1; }
        __syncthreads();                       // drains this iter's STAGE; LDS reads done
    }

    // normalize + write: lane l<32 holds lsum for token l; O rows are reg-mapped
    float l = lsum + __shfl_xor(lsum, 32);
    float inv = 1.f / l;
    #pragma unroll
    for (int r = 0; r < 16; r++) {
        int crow = (r&3) + 8*(r>>2) + 4*hi;
        float invr = __shfl(inv, crow);
        size_t rowo = base + (size_t)(qt*128 + w*32 + crow)*D_;
        #pragma unroll
        for (int db = 0; db < 2; db++)
            Om[rowo + db*32 + l32] = f2bu(oacc[db][r] * invr);
    }
}

// ---------------------------------------------------------------------------
// launch
// ---------------------------------------------------------------------------
extern "C" void kernel_launch(void* const* d_in, const int* in_sizes, int n_in,
                              void* d_out, int out_size, void* d_ws, size_t ws_size,
                              hipStream_t stream)
{
    const unsigned* probe = (const unsigned*)d_in[0];

    unsigned short* u = (unsigned short*)d_ws;
    unsigned short* xc   = u;               size_t o = (size_t)T_*D_;
    unsigned short* wqkv = u + o;           o += (size_t)3*D_*RANK_;
    unsigned short* wOc  = u + o;           o += (size_t)D_*D_;
    unsigned short* Ct   = u + o;           o += (size_t)NZ_*D_;      // 2048 Ct | 64 routers | 64 unused
    unsigned short* h3   = u + o;           o += (size_t)3*T_*RANK_;
    unsigned short* QKb  = u + o;           o += (size_t)2*T_*D_;     // Q | K
    unsigned short* Vtg  = u + o;           o += (size_t)T_*D_;
    unsigned short* z    = u + o;           o += (size_t)T_*NZ_;      // stride ZW_=2048 used
    unsigned short* attnb= u + o;           o += (size_t)T_*D_;
    float* spart = (float*)(u + o);         o += (size_t)8*T_*64*2;   // 8 x T x 64 f32

    unsigned short* Rp = Ct + (size_t)2048*D_;
    unsigned short* Qb = QKb;
    unsigned short* Kb = QKb + (size_t)T_*D_;

    Cvt cv;
    cv.src[0] = d_in[0]; cv.dst[0] = xc;
    cv.src[1] = d_in[3]; cv.dst[1] = Rp;
    cv.src[2] = d_in[4]; cv.dst[2] = Rp + 16384;
    cv.src[3] = d_in[5]; cv.dst[3] = Rp + 32768;
    cv.src[4] = nullptr; cv.dst[4] = Rp + 49152;
    cv.src[5] = d_in[6]; cv.dst[5] = wqkv;
    cv.src[6] = d_in[7]; cv.dst[6] = wqkv + 131072;
    cv.src[7] = d_in[8]; cv.dst[7] = wqkv + 262144;
    cv.src[8] = d_in[9]; cv.dst[8] = wOc;
    cv.C = d_in[2]; cv.Ct = Ct;
    k_inputs<<<512 + 1024, 256, 0, stream>>>(cv, probe);

    k_zscore<<<768, 256, 0, stream>>>(xc, Ct, z, Rp, spart);

    k_hreduce<<<T_/2, 256, 0, stream>>>(z, spart, h3);

    k_qkv2<<<768, 256, 0, stream>>>(h3, wqkv, QKb, Vtg);

    k_flash_mfma<<<dim3(512), 256, 0, stream>>>(Qb, Kb, Vtg, attnb);

    k_mfma_gemm<2,2><<<dim3(T_/64, D_/128), 256, 0, stream>>>(
        attnb, wOc, d_out, probe, T_, D_, D_);
}